// Round 1
// baseline (450.971 us; speedup 1.0000x reference)
//
#include <hip/hip_runtime.h>
#include <hip/hip_bf16.h>

// out[n,m] = t * ( dot(x_n, y_m) - 0.5*(||x_n||^2 + ||y_m||^2) ),  t = temperature * 1.0
// N=16384, M=4096, D=512, fp32 in/out. GEMM via bf16 MFMA (no fp32 MFMA on CDNA4);
// row norms kept in fp32 for precision.

#define NN 16384
#define MM 4096
#define DD 512

using frag_ab = __attribute__((ext_vector_type(8))) short;  // 8 bf16 = 4 VGPRs
using floatx4 = __attribute__((ext_vector_type(4))) float;  // MFMA accumulator

__device__ __forceinline__ unsigned bf16rne(float f) {
    union { float f; unsigned u; } v; v.f = f;
    unsigned u = v.u + 0x7FFFu + ((v.u >> 16) & 1u);   // round-nearest-even
    return u >> 16;
}

__device__ __forceinline__ uint2 cvt4(float4 v) {
    uint2 r;
    r.x = bf16rne(v.x) | (bf16rne(v.y) << 16);
    r.y = bf16rne(v.z) | (bf16rne(v.w) << 16);
    return r;
}

// One wave per row: 64 lanes x 8 floats = 512 = D exactly.
__global__ void rowsq_kernel(const float* __restrict__ v, float* __restrict__ sq) {
    const int lane = threadIdx.x & 63;
    const int row  = blockIdx.x * 4 + (threadIdx.x >> 6);
    const float* p = v + (size_t)row * DD + lane * 8;
    float4 a = *(const float4*)(p);
    float4 b = *(const float4*)(p + 4);
    float s = a.x*a.x + a.y*a.y + a.z*a.z + a.w*a.w
            + b.x*b.x + b.y*b.y + b.z*b.z + b.w*b.w;
    #pragma unroll
    for (int off = 32; off > 0; off >>= 1) s += __shfl_xor(s, off);
    if (lane == 0) sq[row] = s;
}

// 128x128 tile, 256 threads (4 waves in 2x2 of 64x64), BK=32, 16x16x32 bf16 MFMA.
__global__ __launch_bounds__(256) void protonet_gemm(
    const float* __restrict__ x, const float* __restrict__ y,
    const float* __restrict__ xsq, const float* __restrict__ ysq,
    const int* __restrict__ temp, float* __restrict__ out)
{
    __shared__ __align__(16) unsigned short As[128 * 32];
    __shared__ __align__(16) unsigned short Bs[128 * 32];

    const int bn   = blockIdx.x;      // N/128 = 128
    const int bm   = blockIdx.y;      // M/128 = 32
    const int tid  = threadIdx.x;
    const int lane = tid & 63;
    const int wave = tid >> 6;
    const int wn   = wave & 1;        // n-half of tile
    const int wm   = wave >> 1;       // m-half of tile
    const int l15  = lane & 15;
    const int quad = lane >> 4;

    floatx4 acc[4][4] = {};

    for (int k0 = 0; k0 < DD; k0 += 32) {
        // Stage A: 128 rows x 32 k of x, fp32 -> bf16. 1024 float4 chunks, 4/thread.
        #pragma unroll
        for (int i = 0; i < 4; ++i) {
            int c = tid + i * 256;
            int row = c >> 3, col4 = c & 7;
            float4 v = *(const float4*)(x + (size_t)(bn * 128 + row) * DD + k0 + col4 * 4);
            *(uint2*)(&As[row * 32 + col4 * 4]) = cvt4(v);
        }
        // Stage B: 128 rows x 32 k of y.
        #pragma unroll
        for (int i = 0; i < 4; ++i) {
            int c = tid + i * 256;
            int row = c >> 3, col4 = c & 7;
            float4 v = *(const float4*)(y + (size_t)(bm * 128 + row) * DD + k0 + col4 * 4);
            *(uint2*)(&Bs[row * 32 + col4 * 4]) = cvt4(v);
        }
        __syncthreads();

        frag_ab a[4], b[4];
        #pragma unroll
        for (int t = 0; t < 4; ++t) {
            a[t] = *(const frag_ab*)(&As[(wn * 64 + t * 16 + l15) * 32 + quad * 8]);
            b[t] = *(const frag_ab*)(&Bs[(wm * 64 + t * 16 + l15) * 32 + quad * 8]);
        }
        #pragma unroll
        for (int tn = 0; tn < 4; ++tn)
            #pragma unroll
            for (int tm = 0; tm < 4; ++tm)
                acc[tn][tm] = __builtin_amdgcn_mfma_f32_16x16x32_bf16(
                    a[tn], b[tm], acc[tn][tm], 0, 0, 0);
        __syncthreads();
    }

    // Epilogue: C/D layout col=lane&15 (y index), row=quad*4+reg (x index).
    const float t = (float)(*temp);         // TEMP = 1.0
    const int n_base = bn * 128 + wn * 64;
    const int m_base = bm * 128 + wm * 64;
    #pragma unroll
    for (int tn = 0; tn < 4; ++tn) {
        float xs[4];
        #pragma unroll
        for (int r = 0; r < 4; ++r) xs[r] = xsq[n_base + tn * 16 + quad * 4 + r];
        #pragma unroll
        for (int tm = 0; tm < 4; ++tm) {
            const int mcol = m_base + tm * 16 + l15;
            const float ys = ysq[mcol];
            #pragma unroll
            for (int r = 0; r < 4; ++r) {
                const int nrow = n_base + tn * 16 + quad * 4 + r;
                out[(size_t)nrow * MM + mcol] = t * (acc[tn][tm][r] - 0.5f * (xs[r] + ys));
            }
        }
    }
}

extern "C" void kernel_launch(void* const* d_in, const int* in_sizes, int n_in,
                              void* d_out, int out_size, void* d_ws, size_t ws_size,
                              hipStream_t stream) {
    const float* x    = (const float*)d_in[0];
    const float* y    = (const float*)d_in[1];
    const int*   temp = (const int*)d_in[2];
    float* out = (float*)d_out;
    float* xsq = (float*)d_ws;          // 16384 floats
    float* ysq = xsq + NN;              // 4096 floats  (80 KB total << ws)

    rowsq_kernel<<<NN / 4, 256, 0, stream>>>(x, xsq);
    rowsq_kernel<<<MM / 4, 256, 0, stream>>>(y, ysq);
    protonet_gemm<<<dim3(NN / 128, MM / 128), 256, 0, stream>>>(x, y, xsq, ysq, temp, out);
}

// Round 2
// 419.468 us; speedup vs baseline: 1.0751x; 1.0751x over previous
//
#include <hip/hip_runtime.h>
#include <hip/hip_bf16.h>

// out[n,m] = t * ( dot(x_n, y_m) - 0.5*(||x_n||^2 + ||y_m||^2) )
// N=16384, M=4096, D=512, fp32 in/out.
// R2: pre-convert x,y -> bf16 in d_ws (fused with rowsq), then m97-style GEMM:
// global_load_lds width=16 staging into a swizzled [quad][row16][8k] sub-tile
// layout -> conflict-free ds_read_b128 fragment loads (lane l reads offset l*16).

#define NN 16384
#define MM 4096
#define DD 512

using frag_ab = __attribute__((ext_vector_type(8))) short;  // 8 bf16 = 4 VGPRs
using floatx4 = __attribute__((ext_vector_type(4))) float;  // MFMA accumulator

using gas_ptr = const __attribute__((address_space(1))) void*;
using las_ptr = __attribute__((address_space(3))) void*;

__device__ __forceinline__ void async_copy16(const void* g, void* l) {
    __builtin_amdgcn_global_load_lds((gas_ptr)g, (las_ptr)l, 16, 0, 0);
}

__device__ __forceinline__ unsigned bf16rne(float f) {
    union { float f; unsigned u; } v; v.f = f;
    unsigned u = v.u + 0x7FFFu + ((v.u >> 16) & 1u);   // round-nearest-even
    return u >> 16;
}

__device__ __forceinline__ uint2 cvt4(float4 v) {
    uint2 r;
    r.x = bf16rne(v.x) | (bf16rne(v.y) << 16);
    r.y = bf16rne(v.z) | (bf16rne(v.w) << 16);
    return r;
}

// One wave per row (64 lanes x 8 floats = 512 = D): sum-of-squares + bf16 copy.
__global__ void prep_kernel(const float* __restrict__ v, float* __restrict__ sq,
                            unsigned short* __restrict__ vb) {
    const int lane = threadIdx.x & 63;
    const int row  = blockIdx.x * 4 + (threadIdx.x >> 6);
    const float* p = v + (size_t)row * DD + lane * 8;
    float4 a = *(const float4*)(p);
    float4 b = *(const float4*)(p + 4);
    uint2 lo = cvt4(a), hi = cvt4(b);
    *(uint4*)(vb + (size_t)row * DD + lane * 8) = make_uint4(lo.x, lo.y, hi.x, hi.y);
    float s = a.x*a.x + a.y*a.y + a.z*a.z + a.w*a.w
            + b.x*b.x + b.y*b.y + b.z*b.z + b.w*b.w;
    #pragma unroll
    for (int off = 32; off > 0; off >>= 1) s += __shfl_xor(s, off);
    if (lane == 0) sq[row] = s;
}

// Legacy rowsq (fallback path, no bf16 copy).
__global__ void rowsq_kernel(const float* __restrict__ v, float* __restrict__ sq) {
    const int lane = threadIdx.x & 63;
    const int row  = blockIdx.x * 4 + (threadIdx.x >> 6);
    const float* p = v + (size_t)row * DD + lane * 8;
    float4 a = *(const float4*)(p);
    float4 b = *(const float4*)(p + 4);
    float s = a.x*a.x + a.y*a.y + a.z*a.z + a.w*a.w
            + b.x*b.x + b.y*b.y + b.z*b.z + b.w*b.w;
    #pragma unroll
    for (int off = 32; off > 0; off >>= 1) s += __shfl_xor(s, off);
    if (lane == 0) sq[row] = s;
}

// m97-style GEMM on pre-converted bf16. 128x128 tile, 4 waves (2x2 of 64x64),
// BK=32, 16x16x32 MFMA. LDS: 8 A sub-tiles + 8 B sub-tiles of 1 KB, each
// laid out [quad][16 rows][8 k] so fragment ds_read_b128 is lane-linear.
__global__ __launch_bounds__(256) void protonet_gemm_bf(
    const unsigned short* __restrict__ xb, const unsigned short* __restrict__ yb,
    const float* __restrict__ xsq, const float* __restrict__ ysq,
    const int* __restrict__ temp, float* __restrict__ out)
{
    __shared__ __align__(16) unsigned short As[128 * 32];
    __shared__ __align__(16) unsigned short Bs[128 * 32];

    const int bn   = blockIdx.x;      // N/128 = 128
    const int bm   = blockIdx.y;      // M/128 = 32
    const int tid  = threadIdx.x;
    const int lane = tid & 63;
    const int wave = tid >> 6;
    const int wn   = wave & 1;
    const int wm   = wave >> 1;
    const int l15  = lane & 15;
    const int quad = lane >> 4;

    floatx4 acc[4][4] = {};

    // Staging: wave w gathers A sub-tiles {2w, 2w+1} and B sub-tiles {2w, 2w+1}.
    // Lane l loads the 16B (8 bf16, k-contiguous) for row st*16+(l&15),
    // k-quad (l>>4); HW lands it at lds_base + l*16 — exactly where the
    // fragment read for lane l expects it.
    const unsigned short* ga0 = xb + (size_t)(bn * 128 + (wave * 2 + 0) * 16 + l15) * DD + quad * 8;
    const unsigned short* ga1 = xb + (size_t)(bn * 128 + (wave * 2 + 1) * 16 + l15) * DD + quad * 8;
    const unsigned short* gb0 = yb + (size_t)(bm * 128 + (wave * 2 + 0) * 16 + l15) * DD + quad * 8;
    const unsigned short* gb1 = yb + (size_t)(bm * 128 + (wave * 2 + 1) * 16 + l15) * DD + quad * 8;

    for (int k0 = 0; k0 < DD; k0 += 32) {
        async_copy16(ga0 + k0, As + (wave * 2 + 0) * 512);
        async_copy16(ga1 + k0, As + (wave * 2 + 1) * 512);
        async_copy16(gb0 + k0, Bs + (wave * 2 + 0) * 512);
        async_copy16(gb1 + k0, Bs + (wave * 2 + 1) * 512);
        __syncthreads();   // compiler emits vmcnt(0) drain before s_barrier

        frag_ab a[4], b[4];
        #pragma unroll
        for (int t = 0; t < 4; ++t) {
            a[t] = *(const frag_ab*)(As + (wn * 4 + t) * 512 + lane * 8);
            b[t] = *(const frag_ab*)(Bs + (wm * 4 + t) * 512 + lane * 8);
        }
        #pragma unroll
        for (int tn = 0; tn < 4; ++tn)
            #pragma unroll
            for (int tm = 0; tm < 4; ++tm)
                acc[tn][tm] = __builtin_amdgcn_mfma_f32_16x16x32_bf16(
                    a[tn], b[tm], acc[tn][tm], 0, 0, 0);
        __syncthreads();
    }

    // Epilogue: C/D layout col=lane&15 (m index), row=quad*4+reg (n index).
    const float t = (float)(*temp);
    const int n_base = bn * 128 + wn * 64;
    const int m_base = bm * 128 + wm * 64;
    #pragma unroll
    for (int tn = 0; tn < 4; ++tn) {
        float xs[4];
        #pragma unroll
        for (int r = 0; r < 4; ++r) xs[r] = xsq[n_base + tn * 16 + quad * 4 + r];
        #pragma unroll
        for (int tm = 0; tm < 4; ++tm) {
            const int mcol = m_base + tm * 16 + l15;
            const float ys = ysq[mcol];
            #pragma unroll
            for (int r = 0; r < 4; ++r) {
                const int nrow = n_base + tn * 16 + quad * 4 + r;
                out[(size_t)nrow * MM + mcol] = t * (acc[tn][tm][r] - 0.5f * (xs[r] + ys));
            }
        }
    }
}

// Fallback GEMM (R1): converts fp32->bf16 inside the K-loop. Used only if
// ws_size is too small for the bf16 copies.
__global__ __launch_bounds__(256) void protonet_gemm(
    const float* __restrict__ x, const float* __restrict__ y,
    const float* __restrict__ xsq, const float* __restrict__ ysq,
    const int* __restrict__ temp, float* __restrict__ out)
{
    __shared__ __align__(16) unsigned short As[128 * 32];
    __shared__ __align__(16) unsigned short Bs[128 * 32];

    const int bn   = blockIdx.x;
    const int bm   = blockIdx.y;
    const int tid  = threadIdx.x;
    const int lane = tid & 63;
    const int wave = tid >> 6;
    const int wn   = wave & 1;
    const int wm   = wave >> 1;
    const int l15  = lane & 15;
    const int quad = lane >> 4;

    floatx4 acc[4][4] = {};

    for (int k0 = 0; k0 < DD; k0 += 32) {
        #pragma unroll
        for (int i = 0; i < 4; ++i) {
            int c = tid + i * 256;
            int row = c >> 3, col4 = c & 7;
            float4 v = *(const float4*)(x + (size_t)(bn * 128 + row) * DD + k0 + col4 * 4);
            *(uint2*)(&As[row * 32 + col4 * 4]) = cvt4(v);
        }
        #pragma unroll
        for (int i = 0; i < 4; ++i) {
            int c = tid + i * 256;
            int row = c >> 3, col4 = c & 7;
            float4 v = *(const float4*)(y + (size_t)(bm * 128 + row) * DD + k0 + col4 * 4);
            *(uint2*)(&Bs[row * 32 + col4 * 4]) = cvt4(v);
        }
        __syncthreads();

        frag_ab a[4], b[4];
        #pragma unroll
        for (int t = 0; t < 4; ++t) {
            a[t] = *(const frag_ab*)(&As[(wn * 64 + t * 16 + l15) * 32 + quad * 8]);
            b[t] = *(const frag_ab*)(&Bs[(wm * 64 + t * 16 + l15) * 32 + quad * 8]);
        }
        #pragma unroll
        for (int tn = 0; tn < 4; ++tn)
            #pragma unroll
            for (int tm = 0; tm < 4; ++tm)
                acc[tn][tm] = __builtin_amdgcn_mfma_f32_16x16x32_bf16(
                    a[tn], b[tm], acc[tn][tm], 0, 0, 0);
        __syncthreads();
    }

    const float t = (float)(*temp);
    const int n_base = bn * 128 + wn * 64;
    const int m_base = bm * 128 + wm * 64;
    #pragma unroll
    for (int tn = 0; tn < 4; ++tn) {
        float xs[4];
        #pragma unroll
        for (int r = 0; r < 4; ++r) xs[r] = xsq[n_base + tn * 16 + quad * 4 + r];
        #pragma unroll
        for (int tm = 0; tm < 4; ++tm) {
            const int mcol = m_base + tm * 16 + l15;
            const float ys = ysq[mcol];
            #pragma unroll
            for (int r = 0; r < 4; ++r) {
                const int nrow = n_base + tn * 16 + quad * 4 + r;
                out[(size_t)nrow * MM + mcol] = t * (acc[tn][tm][r] - 0.5f * (xs[r] + ys));
            }
        }
    }
}

extern "C" void kernel_launch(void* const* d_in, const int* in_sizes, int n_in,
                              void* d_out, int out_size, void* d_ws, size_t ws_size,
                              hipStream_t stream) {
    const float* x    = (const float*)d_in[0];
    const float* y    = (const float*)d_in[1];
    const int*   temp = (const int*)d_in[2];
    float* out = (float*)d_out;

    float* xsq = (float*)d_ws;                       // 16384 f  (64 KB)
    float* ysq = xsq + NN;                           // 4096 f   (16 KB)
    unsigned short* xb = (unsigned short*)(ysq + MM);   // 16 MB
    unsigned short* yb = xb + (size_t)NN * DD;          // 4 MB

    const size_t need = (size_t)(NN + MM) * 4 + (size_t)(NN + MM) * DD * 2;

    if (ws_size >= need) {
        prep_kernel<<<NN / 4, 256, 0, stream>>>(x, xsq, xb);
        prep_kernel<<<MM / 4, 256, 0, stream>>>(y, ysq, yb);
        protonet_gemm_bf<<<dim3(NN / 128, MM / 128), 256, 0, stream>>>(
            xb, yb, xsq, ysq, temp, out);
    } else {
        rowsq_kernel<<<NN / 4, 256, 0, stream>>>(x, xsq);
        rowsq_kernel<<<MM / 4, 256, 0, stream>>>(y, ysq);
        protonet_gemm<<<dim3(NN / 128, MM / 128), 256, 0, stream>>>(
            x, y, xsq, ysq, temp, out);
    }
}